// Round 1
// baseline (289.158 us; speedup 1.0000x reference)
//
#include <hip/hip_runtime.h>

#define NX 160
#define NY 192
#define NZ 160
#define WIN 21
#define HALF 10
#define NTOT (NX * NY * NZ)   // 4,915,200

#define ZC 32                 // z-chunk per block in pass_zy
#define ZH (ZC + 2 * HALF)    // 52 (z with halo)
#define PROW 53               // padded row for p (avoid 8-way bank conflict)
#define QROW 33               // padded row for q

#define XC 40                 // x-chunk per thread in pass_x

// ---------------------------------------------------------------------------
// Pass 1: per x-slice, compute field product and box-filter along z then y.
// F: 0=I, 1=J, 2=I*I, 3=J*J, 4=I*J
// grid = (NX, NZ/ZC), block = 256
// ---------------------------------------------------------------------------
template <int F>
__global__ __launch_bounds__(256) void pass_zy(const float* __restrict__ I,
                                               const float* __restrict__ J,
                                               float* __restrict__ B) {
    __shared__ float p[NY * PROW];  // product tile, z with halo (40.7 KB)
    __shared__ float q[NY * QROW];  // z-filtered tile (25.3 KB)

    const int bx = blockIdx.x;       // x slice
    const int z0 = blockIdx.y * ZC;  // z chunk origin
    const int tid = threadIdx.x;

    const float* baseI = I + (size_t)bx * (NY * NZ);
    const float* baseJ = J + (size_t)bx * (NY * NZ);

    // ---- load + pointwise product (zero-padded z halo) ----
    for (int idx = tid; idx < NY * ZH; idx += 256) {
        const int y = idx / ZH;
        const int zl = idx - y * ZH;
        const int gz = z0 - HALF + zl;
        float v = 0.0f;
        if (gz >= 0 && gz < NZ) {
            const int g = y * NZ + gz;
            if (F == 0) v = baseI[g];
            else if (F == 1) v = baseJ[g];
            else if (F == 2) { const float a = baseI[g]; v = a * a; }
            else if (F == 3) { const float a = baseJ[g]; v = a * a; }
            else { v = baseI[g] * baseJ[g]; }
        }
        p[y * PROW + zl] = v;
    }
    __syncthreads();

    // ---- slide along z: each thread owns one y-row, running sum ----
    if (tid < NY) {
        const float* pr = p + tid * PROW;
        float s = 0.0f;
#pragma unroll
        for (int k = 0; k < WIN; ++k) s += pr[k];
        float* qr = q + tid * QROW;
        qr[0] = s;
        for (int zq = 1; zq < ZC; ++zq) {
            s += pr[zq + WIN - 1] - pr[zq - 1];
            qr[zq] = s;
        }
    }
    __syncthreads();

    // ---- slide along y (zero-padded edges), write out ----
    {
        const int z = tid & 31;        // 0..31 within chunk
        const int seg = tid >> 5;      // 0..7, each covers 24 y's
        const int y0 = seg * 24;
        float s = 0.0f;
        for (int k = -HALF; k <= HALF; ++k) {
            const int yy = y0 + k;
            if (yy >= 0 && yy < NY) s += q[yy * QROW + z];
        }
        float* out = B + ((size_t)bx * NY) * NZ + z0 + z;
        for (int j = 0; j < 24; ++j) {
            const int y = y0 + j;
            out[(size_t)y * NZ] = s;
            const int ya = y + HALF + 1;
            const int yr = y - HALF;
            const float add = (ya < NY) ? q[ya * QROW + z] : 0.0f;
            const float sub = (yr >= 0) ? q[yr * QROW + z] : 0.0f;
            s += add - sub;
        }
    }
}

// ---------------------------------------------------------------------------
// Pass 2: slide along x (stride NY*NZ) for all 5 fields with running sums,
// compute cc per voxel, reduce, atomic-accumulate.
// grid = (NY*NZ/256, NX/XC), block = 256
// ---------------------------------------------------------------------------
__global__ __launch_bounds__(256) void pass_x_cc(const float* __restrict__ B,
                                                 float* __restrict__ acc) {
    const int SX = NY * NZ;  // 30720
    const int col = blockIdx.x * 256 + threadIdx.x;  // (y*NZ + z)
    const int x0 = blockIdx.y * XC;

    const float* b0 = B + col;
    const float* b1 = b0 + NTOT;
    const float* b2 = b1 + NTOT;
    const float* b3 = b2 + NTOT;
    const float* b4 = b3 + NTOT;

    float sI = 0.f, sJ = 0.f, sI2 = 0.f, sJ2 = 0.f, sIJ = 0.f;
    for (int k = -HALF; k <= HALF; ++k) {
        const int xx = x0 + k;
        if (xx >= 0 && xx < NX) {
            const int o = xx * SX;
            sI += b0[o]; sJ += b1[o]; sI2 += b2[o]; sJ2 += b3[o]; sIJ += b4[o];
        }
    }

    const float n = (float)(WIN * WIN * WIN);
    const float inv_n = 1.0f / n;
    float local = 0.0f;
#pragma unroll 2
    for (int j = 0; j < XC; ++j) {
        const int x = x0 + j;
        // replicate reference's expanded-form arithmetic (f32)
        const float uI = sI * inv_n;
        const float uJ = sJ * inv_n;
        const float cross = sIJ - uJ * sI - uI * sJ + uI * uJ * n;
        const float Ivar = sI2 - 2.0f * uI * sI + uI * uI * n;
        const float Jvar = sJ2 - 2.0f * uJ * sJ + uJ * uJ * n;
        const float cc = cross * cross / (Ivar * Jvar + 1e-5f);
        local += cc;
        const int xa = x + HALF + 1;
        const int xr = x - HALF;
        if (xa < NX) {
            const int o = xa * SX;
            sI += b0[o]; sJ += b1[o]; sI2 += b2[o]; sJ2 += b3[o]; sIJ += b4[o];
        }
        if (xr >= 0) {
            const int o = xr * SX;
            sI -= b0[o]; sJ -= b1[o]; sI2 -= b2[o]; sJ2 -= b3[o]; sIJ -= b4[o];
        }
    }

    // block reduction: wave shuffle then LDS
    const int lane = threadIdx.x & 63;
    const int wid = threadIdx.x >> 6;
    for (int off = 32; off; off >>= 1) local += __shfl_down(local, off);
    __shared__ float red[4];
    if (lane == 0) red[wid] = local;
    __syncthreads();
    if (threadIdx.x == 0) {
        atomicAdd(acc, red[0] + red[1] + red[2] + red[3]);
    }
}

__global__ void finalize_k(const float* __restrict__ acc, float* __restrict__ out) {
    out[0] = 1.0f - acc[0] / (float)NTOT;
}

extern "C" void kernel_launch(void* const* d_in, const int* in_sizes, int n_in,
                              void* d_out, int out_size, void* d_ws, size_t ws_size,
                              hipStream_t stream) {
    const float* I = (const float*)d_in[0];
    const float* J = (const float*)d_in[1];
    float* out = (float*)d_out;

    float* acc = (float*)d_ws;                       // 1 float accumulator
    float* B = (float*)((char*)d_ws + 256);          // 5 * NTOT floats

    hipMemsetAsync(d_ws, 0, 256, stream);

    dim3 gzy(NX, NZ / ZC);
    pass_zy<0><<<gzy, 256, 0, stream>>>(I, J, B + 0L * NTOT);
    pass_zy<1><<<gzy, 256, 0, stream>>>(I, J, B + 1L * NTOT);
    pass_zy<2><<<gzy, 256, 0, stream>>>(I, J, B + 2L * NTOT);
    pass_zy<3><<<gzy, 256, 0, stream>>>(I, J, B + 3L * NTOT);
    pass_zy<4><<<gzy, 256, 0, stream>>>(I, J, B + 4L * NTOT);

    dim3 gx(NY * NZ / 256, NX / XC);
    pass_x_cc<<<gx, 256, 0, stream>>>(B, acc);

    finalize_k<<<1, 1, 0, stream>>>(acc, out);
}